// Round 10
// baseline (172.533 us; speedup 1.0000x reference)
//
#include <hip/hip_runtime.h>
#include <hip/hip_bf16.h>
#include <math.h>

#define NB 65536
#define DIN 1024
#define NQ 64
#define DOUT 1024

typedef __attribute__((ext_vector_type(8))) short bf16x8;
typedef __attribute__((ext_vector_type(4))) float f32x4;
typedef unsigned short u16;

__device__ __forceinline__ u16 f2bf(float f) {
    union { float f; unsigned u; } v; v.f = f;
    return (u16)((v.u + 0x7fffu + ((v.u >> 16) & 1u)) >> 16);
}

// async global->LDS DMA. dest = wave-uniform base + lane*size. vmcnt-tracked.
__device__ __forceinline__ void gll16(const void* g, void* l) {
    __builtin_amdgcn_global_load_lds(
        (const __attribute__((address_space(1))) unsigned int*)g,
        (__attribute__((address_space(3))) unsigned int*)l, 16, 0, 0);
}
__device__ __forceinline__ void gll4(const void* g, void* l) {
    __builtin_amdgcn_global_load_lds(
        (const __attribute__((address_space(1))) unsigned int*)g,
        (__attribute__((address_space(3))) unsigned int*)l, 4, 0, 0);
}

// ---- kP: bf16 weights in FRAGMENT-MAJOR order + per-q constants -------------
__global__ __launch_bounds__(256) void kP(const float* __restrict__ W_in,
                                          const float* __restrict__ W_out,
                                          const float* __restrict__ qp,
                                          u16* __restrict__ Wbf,
                                          u16* __restrict__ Wobf,
                                          float* __restrict__ cp0,
                                          float* __restrict__ cq) {
    int tid = blockIdx.x * 256 + threadIdx.x;       // 0..65535
    {
        int j = tid & 7, l = (tid >> 3) & 63, n = (tid >> 9) & 3, c = tid >> 11;
        int row = n * 16 + (l & 15);
        int k   = c * 32 + (l >> 4) * 8 + j;
        Wbf[tid] = f2bf(W_in[row * DIN + k]);
    }
    {
        int j = tid & 7, l = (tid >> 3) & 63, kf = (tid >> 9) & 1, n = tid >> 10;
        int col = n * 16 + (l & 15);
        int k   = kf * 32 + (l >> 4) * 8 + j;
        Wobf[tid] = f2bf(W_out[col * NQ + k]);
    }
    if (tid < NQ) {
        cp0[tid] = cosf(qp[tid * 3 + 0]);
        cq[tid]  = sinf(qp[tid * 3 + 1]) * cosf(qp[tid * 3 + 2]);
    }
}

// ---- kF: DRAM-friendly bursts + counted-vmcnt LDS rings, zero barriers ------
// 4096 blocks x 64 threads (1 wave, 16 rows). x staged in PIECES: 8 gll16/piece,
// each 512B-contiguous per row (2 rows/op), ring depth 3. Output through LDS
// outstage, stored as 16 x 1KB-contiguous dwordx4 bursts. All VMEM = gll/asm;
// wait counts = exact #ops-newer-than-target (in-order vmcnt retirement).
__global__ __launch_bounds__(64) void kF(const float* __restrict__ x,
                                         const u16* __restrict__ Wbf,
                                         const float* __restrict__ b_in,
                                         const float* __restrict__ cp0,
                                         const float* __restrict__ cq,
                                         const u16* __restrict__ Wobf,
                                         const float* __restrict__ b_out,
                                         float* __restrict__ out) {
    // arena layout (phase A): xring [0,24576) 3x8192 | wbring [24576,36864) 3x4096
    // (phase B, overlaying dead A slots): outstage [0,16384) | wobring [16384,32768)
    // st [36864,39168) | binL 39168 | cp0L 39424 | cqL 39680 | boutL [39936,44032)
    __shared__ __align__(16) char arena[44032];

    const int l = threadIdx.x;
    const int r = l & 15, kg = l >> 4;
    const int r7 = r & 7;
    const int row0 = blockIdx.x * 16;

    float* binL  = (float*)(arena + 39168);
    float* cp0L  = (float*)(arena + 39424);
    float* cqL   = (float*)(arena + 39680);
    float* boutL = (float*)(arena + 39936);
    u16 (*st)[72] = (u16(*)[72])(arena + 36864);

    // ---- prologue consts: 7 oldest vmcnt ops ----
    gll4(b_in + l, arena + 39168);
    gll4(cp0 + l, arena + 39424);
    gll4(cq  + l, arena + 39680);
    gll16(b_out + l * 4 +   0, arena + 39936);
    gll16(b_out + l * 4 + 256, arena + 39936 + 1024);
    gll16(b_out + l * 4 + 512, arena + 39936 + 2048);
    gll16(b_out + l * 4 + 768, arena + 39936 + 3072);

    // x piece staging: op j covers rows 2j (lanes 0-31) / 2j+1 (lanes 32-63),
    // 512 B contiguous each. Source 16B-unit pre-XORed by (row&7) so the
    // linear LDS dest holds stored[u] = orig[u ^ (row&7)] (bank-floor reads).
    const int h = l >> 5;
    const int q32 = (l & 31) ^ h;
    const char* xbase = (const char*)x + (size_t)(row0 + h) * 4096;

#define STAGE_P(p) { char* d_ = arena + ((p) % 3) * 8192; \
    _Pragma("unroll") \
    for (int j_ = 0; j_ < 8; ++j_) { \
        const char* s_ = xbase + (size_t)(2 * j_) * 4096 + (p) * 512 \
                         + ((q32 ^ ((j_ & 3) << 1)) * 16); \
        gll16(s_, d_ + j_ * 1024); } }

#define STAGE_W(t) { char* d_ = arena + 24576 + ((t) % 3) * 4096; \
    const char* s_ = (const char*)Wbf + (size_t)(t) * 4096 + l * 16; \
    gll16(s_, d_); gll16(s_ + 1024, d_ + 1024); \
    gll16(s_ + 2048, d_ + 2048); gll16(s_ + 3072, d_ + 3072); }

#define STAGE_G(k) { char* d_ = arena + 16384 + ((k) % 4) * 4096; \
    const char* s_ = (const char*)Wobf + (size_t)(k) * 4096 + l * 16; \
    gll16(s_, d_); gll16(s_ + 1024, d_ + 1024); \
    gll16(s_ + 2048, d_ + 2048); gll16(s_ + 3072, d_ + 3072); }

#define VMW(n) { asm volatile("s_waitcnt vmcnt(" #n ")" ::: "memory"); \
                 __builtin_amdgcn_sched_barrier(0); }

    STAGE_P(0) STAGE_P(1) STAGE_W(0) STAGE_W(1)    // 16 + 8 ops

    // ---------------- Phase A: GEMM1, 32 chunks of BK=32 ----------------
    f32x4 acc[4] = {f32x4{0,0,0,0}, f32x4{0,0,0,0}, f32x4{0,0,0,0}, f32x4{0,0,0,0}};

    #pragma unroll
    for (int t = 0; t < 32; ++t) {
        if (t + 2 <= 31) STAGE_W(t + 2)                      // 4 ops
        if ((t & 3) == 0 && t <= 20) STAGE_P((t >> 2) + 2)   // 8 ops, after W
        if (t == 31) { STAGE_G(0) STAGE_G(1) STAGE_G(2) }    // B prefetch
        // N = exact #ops newer than Wb(t):
        const int NA = (t <= 22 && (t & 3) <= 2) ? 16
                     : (t <= 29 ? 8 : (t == 30 ? 4 : 12));
        if (NA == 16) VMW(16) else if (NA == 8) VMW(8)
        else if (NA == 4) VMW(4) else VMW(12)

        const char* xb_ = arena + ((t >> 2) % 3) * 8192 + r * 512;
        const int s = t & 3;
        f32x4 xa = *(const f32x4*)(xb_ + (((s * 8 + kg * 2 + 0) ^ r7) * 16));
        f32x4 xc = *(const f32x4*)(xb_ + (((s * 8 + kg * 2 + 1) ^ r7) * 16));
        union { bf16x8 v; unsigned u[4]; } a;
        asm("v_cvt_pk_bf16_f32 %0, %1, %2" : "=v"(a.u[0]) : "v"(xa[0]), "v"(xa[1]));
        asm("v_cvt_pk_bf16_f32 %0, %1, %2" : "=v"(a.u[1]) : "v"(xa[2]), "v"(xa[3]));
        asm("v_cvt_pk_bf16_f32 %0, %1, %2" : "=v"(a.u[2]) : "v"(xc[0]), "v"(xc[1]));
        asm("v_cvt_pk_bf16_f32 %0, %1, %2" : "=v"(a.u[3]) : "v"(xc[2]), "v"(xc[3]));
        const char* wb_ = arena + 24576 + (t % 3) * 4096;
        #pragma unroll
        for (int n = 0; n < 4; ++n) {
            bf16x8 b = *(const bf16x8*)(wb_ + n * 1024 + l * 16);
            acc[n] = __builtin_amdgcn_mfma_f32_16x16x32_bf16(a.v, b, acc[n], 0, 0, 0);
        }
    }

    // ---------------- quantum epilogue -> st (wave-private) ----------------
    #pragma unroll
    for (int n = 0; n < 4; ++n) {
        int q = n * 16 + r;
        float bi = binL[q], c0q = cp0L[q], c1q = cqL[q];
        #pragma unroll
        for (int i = 0; i < 4; ++i) {
            float av = acc[n][i] + bi;
            float e2 = __builtin_amdgcn_exp2f(av * 2.8853900817779268f);
            float th = 1.0f - 2.0f * __builtin_amdgcn_rcpf(e2 + 1.0f);
            float sv = __builtin_amdgcn_cosf(th * 0.25f) * c0q + c1q;
            st[kg * 4 + i][q] = f2bf(sv);
        }
    }
    bf16x8 sa0 = *(const bf16x8*)&st[r][kg * 8];
    bf16x8 sa1 = *(const bf16x8*)&st[r][32 + kg * 8];

    // ---------------- Phase B: GEMM2, 32 groups; 1KB-burst stores ----------
    float* outst = (float*)arena;                    // [16][256] f32
    #pragma unroll
    for (int k = 0; k < 32; ++k) {
        if (k + 3 <= 31) STAGE_G(k + 3)              // 4 ops
        // N = loads(k+1..k+3) + 16 stores if a burst happened in last 3 iters
        const int NBw = (k >= 8 && (k & 7) <= 2) ? 28
                      : (k <= 28 ? 12 : (k == 29 ? 8 : (k == 30 ? 4 : 0)));
        if (NBw == 28) VMW(28) else if (NBw == 12) VMW(12)
        else if (NBw == 8) VMW(8) else if (NBw == 4) VMW(4) else VMW(0)

        const char* gb = arena + 16384 + (k % 4) * 4096;
        #pragma unroll
        for (int ti = 0; ti < 2; ++ti) {
            bf16x8 b0 = *(const bf16x8*)(gb + ti * 2048 + l * 16);
            bf16x8 b1 = *(const bf16x8*)(gb + ti * 2048 + 1024 + l * 16);
            f32x4 a2 = {0.0f, 0.0f, 0.0f, 0.0f};
            a2 = __builtin_amdgcn_mfma_f32_16x16x32_bf16(sa0, b0, a2, 0, 0, 0);
            a2 = __builtin_amdgcn_mfma_f32_16x16x32_bf16(sa1, b1, a2, 0, 0, 0);
            const int tile = 2 * k + ti;
            const int c0 = ((tile & 15) << 4) + r;   // col within 256-col block
            float bo = boutL[tile * 16 + r];
            #pragma unroll
            for (int i = 0; i < 4; ++i)
                outst[(kg * 4 + i) * 256 + c0] = a2[i] + bo;
        }
        if ((k & 7) == 7) {                          // col-block done: burst
            const int cb = k >> 3;
            #pragma unroll
            for (int j = 0; j < 16; ++j) {
                f32x4 v = *(const f32x4*)((const char*)outst + j * 1024 + l * 16);
                const char* oS = (const char*)out + (size_t)(row0 + j) * 4096;
                if (cb == 0)
                    asm volatile("global_store_dwordx4 %0, %1, %2 offset:0"
                                 :: "v"(l * 16), "v"(v), "s"(oS) : "memory");
                else if (cb == 1)
                    asm volatile("global_store_dwordx4 %0, %1, %2 offset:1024"
                                 :: "v"(l * 16), "v"(v), "s"(oS) : "memory");
                else if (cb == 2)
                    asm volatile("global_store_dwordx4 %0, %1, %2 offset:2048"
                                 :: "v"(l * 16), "v"(v), "s"(oS) : "memory");
                else
                    asm volatile("global_store_dwordx4 %0, %1, %2 offset:3072"
                                 :: "v"(l * 16), "v"(v), "s"(oS) : "memory");
            }
        }
    }
#undef STAGE_P
#undef STAGE_W
#undef STAGE_G
#undef VMW
}

extern "C" void kernel_launch(void* const* d_in, const int* in_sizes, int n_in,
                              void* d_out, int out_size, void* d_ws, size_t ws_size,
                              hipStream_t stream) {
    const float* x    = (const float*)d_in[0];
    const float* W_in = (const float*)d_in[1];
    const float* b_in = (const float*)d_in[2];
    const float* qp   = (const float*)d_in[3];
    const float* W_out= (const float*)d_in[4];
    const float* b_out= (const float*)d_in[5];
    float* out = (float*)d_out;

    char* ws = (char*)d_ws;
    u16*   Wbf  = (u16*)(ws);              // 128 KB fragment-major W_in
    u16*   Wobf = (u16*)(ws + 131072);     // 128 KB fragment-major W_out
    float* cp0  = (float*)(ws + 262144);   // 256 B
    float* cq   = (float*)(ws + 262400);   // 256 B

    kP<<<256, 256, 0, stream>>>(W_in, W_out, qp, Wbf, Wobf, cp0, cq);
    kF<<<NB / 16, 64, 0, stream>>>(x, Wbf, b_in, cp0, cq, Wobf, b_out, out);
}